// Round 2
// baseline (168.049 us; speedup 1.0000x reference)
//
#include <hip/hip_runtime.h>
#include <hip/hip_bf16.h>

#define B_ 4
#define N_ 4096
#define L_ 4104
#define D_ 512
#define BK 64
#define NF 210     // monomials of degree <=6 in 4 vars
#define ZCH 36     // k_zphi chunk length (multiple of 12 -> aligned pooling windows)
#define ZCHUNKS 114  // 114*36 == 4104 == L_

typedef __attribute__((ext_vector_type(8))) short bf16x8;
typedef __attribute__((ext_vector_type(4))) float f32x4;

// ---------------- K0: G_k = bf16(emb*cw_k) @ bf16(W)^T  + bias' + feature table -------
__global__ __launch_bounds__(256) void k_g(const float* __restrict__ emb,
    const float* __restrict__ pw, const float* __restrict__ cwp,
    const float* __restrict__ cb, const float* __restrict__ pb,
    float* __restrict__ G, float* __restrict__ biasp,
    unsigned* __restrict__ featPk, float* __restrict__ featCf,
    float* __restrict__ Zg) {
  __shared__ __align__(16) __hip_bfloat16 As[2][64 * BK];
  __shared__ __align__(16) __hip_bfloat16 Bs[2][128 * BK];
  __shared__ __align__(16) float cwS[512];
  __shared__ float red[4];
  const int bx = blockIdx.x;
  const int t = threadIdx.x;
  const int w = t >> 6, l = t & 63;

  if (bx == 128) {                       // feature table + zero moment buffer
    for (int zi = t; zi < B_ * NF * 5; zi += 256) Zg[zi] = 0.f;
    if (t < NF) {
      int idx = 0, mp = 0, mq = 0, mr = 0, ms = 0;
      for (int m = 0; m <= 6; ++m)
        for (int p = m; p >= 0; --p)
          for (int q = m - p; q >= 0; --q)
            for (int r = m - p - q; r >= 0; --r) {
              const int s4 = m - p - q - r;
              if (idx == t) { mp = p; mq = q; mr = r; ms = s4; }
              ++idx;
            }
      featPk[t] = (unsigned)mp | ((unsigned)mq << 8) | ((unsigned)mr << 16) | ((unsigned)ms << 24);
      const float invf[7] = {1.f, 1.f, 0.5f, 1.f/6.f, 1.f/24.f, 1.f/120.f, 1.f/720.f};
      featCf[t] = invf[mp] * invf[mq] * invf[mr] * invf[ms];
    }
    return;
  }
  if (bx >= 64) {                        // bias'[o] = cb . W[o,:] + pb[o]
    const int o0 = (bx - 64) * 8;
    const float2 cv = *(const float2*)(cb + t * 2);
#pragma unroll
    for (int oo = 0; oo < 8; ++oo) {
      const int o = o0 + oo;
      const float2 wv = *(const float2*)(pw + (size_t)o * 512 + t * 2);
      float s = wv.x * cv.x + wv.y * cv.y;
#pragma unroll
      for (int off = 32; off > 0; off >>= 1) s += __shfl_xor(s, off);
      if (l == 0) red[w] = s;
      __syncthreads();
      if (t == 0) biasp[o] = red[0] + red[1] + red[2] + red[3] + pb[o];
      __syncthreads();
    }
    return;
  }

  const int m0 = (bx & 3) * 64;          // token tile
  const int n0 = ((bx >> 2) & 3) * 128;  // output-channel tile
  const int kp = bx >> 4;                // conv tap 0..3
  const int quad = l >> 4, r16 = l & 15;
  const int wc = w * 32;

  cwS[t]       = cwp[t * 4 + kp];
  cwS[t + 256] = cwp[(t + 256) * 4 + kp];

  f32x4 acc[4][2];
#pragma unroll
  for (int a = 0; a < 4; ++a)
#pragma unroll
    for (int bq = 0; bq < 2; ++bq) acc[a][bq] = (f32x4){0.f, 0.f, 0.f, 0.f};

  const int ra = t >> 2, ga0 = (t & 3) * 2;
  const int rb = t >> 1, gb0 = (t & 1) * 4;

#define STAGEG(buf, kb)                                                          \
  _Pragma("unroll")                                                              \
  for (int gi = 0; gi < 2; ++gi) {                                               \
    const int g = ga0 + gi;                                                      \
    const int c0 = (kb) + g * 8;                                                 \
    const float4 a0 = *(const float4*)(emb + (size_t)(m0 + ra) * 512 + c0);      \
    const float4 a1 = *(const float4*)(emb + (size_t)(m0 + ra) * 512 + c0 + 4);  \
    const float4 w0 = *(const float4*)(cwS + c0);                                \
    const float4 w1 = *(const float4*)(cwS + c0 + 4);                            \
    union { __hip_bfloat16 q[8]; bf16x8 v; } ua;                                 \
    ua.q[0] = __float2bfloat16(a0.x * w0.x); ua.q[1] = __float2bfloat16(a0.y * w0.y); \
    ua.q[2] = __float2bfloat16(a0.z * w0.z); ua.q[3] = __float2bfloat16(a0.w * w0.w); \
    ua.q[4] = __float2bfloat16(a1.x * w1.x); ua.q[5] = __float2bfloat16(a1.y * w1.y); \
    ua.q[6] = __float2bfloat16(a1.z * w1.z); ua.q[7] = __float2bfloat16(a1.w * w1.w); \
    *(bf16x8*)(&As[buf][ra * BK + ((g ^ (ra & 7)) * 8)]) = ua.v;                 \
  }                                                                              \
  _Pragma("unroll")                                                              \
  for (int gi = 0; gi < 4; ++gi) {                                               \
    const int g = gb0 + gi;                                                      \
    const int c0 = (kb) + g * 8;                                                 \
    const float4 b0 = *(const float4*)(pw + (size_t)(n0 + rb) * 512 + c0);       \
    const float4 b1 = *(const float4*)(pw + (size_t)(n0 + rb) * 512 + c0 + 4);   \
    union { __hip_bfloat16 q[8]; bf16x8 v; } ub;                                 \
    ub.q[0] = __float2bfloat16(b0.x); ub.q[1] = __float2bfloat16(b0.y);          \
    ub.q[2] = __float2bfloat16(b0.z); ub.q[3] = __float2bfloat16(b0.w);          \
    ub.q[4] = __float2bfloat16(b1.x); ub.q[5] = __float2bfloat16(b1.y);          \
    ub.q[6] = __float2bfloat16(b1.z); ub.q[7] = __float2bfloat16(b1.w);          \
    *(bf16x8*)(&Bs[buf][rb * BK + ((g ^ (rb & 7)) * 8)]) = ub.v;                 \
  }

  __syncthreads();        // cwS ready
  STAGEG(0, 0)
  __syncthreads();

#pragma unroll 1
  for (int kt = 0; kt < 8; ++kt) {
    const int cur = kt & 1;
    if (kt < 7) { STAGEG(1 - cur, (kt + 1) * BK) }
#pragma unroll
    for (int kk = 0; kk < 2; ++kk) {
      const int col_e = (kk * 32 + quad * 8) ^ ((r16 & 7) * 8);
      bf16x8 af[4], bfr[2];
#pragma unroll
      for (int ti = 0; ti < 4; ++ti)
        af[ti] = *(const bf16x8*)(&As[cur][(ti * 16 + r16) * BK + col_e]);
#pragma unroll
      for (int tj = 0; tj < 2; ++tj)
        bfr[tj] = *(const bf16x8*)(&Bs[cur][(wc + tj * 16 + r16) * BK + col_e]);
#pragma unroll
      for (int ti = 0; ti < 4; ++ti)
#pragma unroll
        for (int tj = 0; tj < 2; ++tj)
          acc[ti][tj] = __builtin_amdgcn_mfma_f32_16x16x32_bf16(af[ti], bfr[tj], acc[ti][tj], 0, 0, 0);
    }
    __syncthreads();
  }
#undef STAGEG

#pragma unroll
  for (int ti = 0; ti < 4; ++ti) {
    const int gi0 = m0 + ti * 16 + quad * 4;
#pragma unroll
    for (int tj = 0; tj < 2; ++tj) {
      const int go = n0 + wc + tj * 16 + r16;
#pragma unroll
      for (int r = 0; r < 4; ++r)
        G[((size_t)kp * 256 + gi0 + r) * 512 + go] = acc[ti][tj][r];
    }
  }
}

// helper: 4-way softmax from a t-window in LDS
__device__ __forceinline__ float4 softmax4(const float* __restrict__ tw, int base,
                                           int i, float bb) {
  const float s0 = tw[i - base] + bb;
  const int j2 = i & ~1;
  const float s1 = (tw[j2 - base] + tw[j2 + 1 - base]) * 0.5f + bb;
  const int j3 = (i / 3) * 3;
  const float s2 = (tw[j3 - base] + tw[j3 + 1 - base] + tw[j3 + 2 - base]) * (1.f / 3.f) + bb;
  const int j4 = i & ~3;
  const float s3 = (tw[j4 - base] + tw[j4 + 1 - base] + tw[j4 + 2 - base] + tw[j4 + 3 - base]) * 0.25f + bb;
  const float m = fmaxf(fmaxf(s0, s1), fmaxf(s2, s3));
  const float e0 = __expf(s0 - m), e1 = __expf(s1 - m), e2 = __expf(s2 - m), e3 = __expf(s3 - m);
  const float inv = 1.f / (e0 + e1 + e2 + e3);
  return make_float4(e0 * inv, e1 * inv, e2 * inv, e3 * inv);
}

// ---------------- K1: j-side moments  Z[alpha] = sum_j s_j^alpha * [s_j;1]
// t-window computed in-block from G row gathers (coalesced, L2-resident)
__global__ __launch_bounds__(256) void k_zphi(const int* __restrict__ x,
    const float* __restrict__ G, const float* __restrict__ biasp,
    const float* __restrict__ sw, const float* __restrict__ sb,
    const unsigned* __restrict__ featPk, float* __restrict__ Zg) {
  __shared__ float twj[ZCH];
  __shared__ float P[ZCH][32];           // powers 0..7 of each of 4 components per j
  __shared__ unsigned pkS[NF];
  __shared__ int tokS[ZCH + 3];
  __shared__ float rpart[ZCH][4];
  const int bx = blockIdx.x;             // B_*ZCHUNKS
  const int b = bx / ZCHUNKS, jc = bx % ZCHUNKS;
  const int t = threadIdx.x, d = t * 2, w = t >> 6, l = t & 63;
  const int j0 = jc * ZCH;               // multiple of 12 -> pooling windows stay in-tile
  if (t < NF) pkS[t] = featPk[t];
  if (t < ZCH + 3) {
    const int j = j0 + t;
    tokS[t] = (j < N_) ? x[b * N_ + j] : -1;
  }
  __syncthreads();
  const float2 swv = *(const float2*)(sw + d);
  const float2 bp  = *(const float2*)(biasp + d);
  const float cpart = bp.x * swv.x + bp.y * swv.y;
#pragma unroll 2
  for (int jj = 0; jj < ZCH; ++jj) {
    float s = 0.f;
    if (j0 + jj < N_) {
      s = cpart;
#pragma unroll
      for (int k = 0; k < 4; ++k) {
        const int tk = tokS[jj + k];
        if (tk >= 0) {
          const float2 g = *(const float2*)(G + ((size_t)k * 256 + tk) * 512 + d);
          s += g.x * swv.x + g.y * swv.y;
        }
      }
    }
#pragma unroll
    for (int off = 32; off > 0; off >>= 1) s += __shfl_xor(s, off);
    if (l == 0) rpart[jj][w] = s;
  }
  __syncthreads();
  if (t < ZCH) twj[t] = rpart[t][0] + rpart[t][1] + rpart[t][2] + rpart[t][3];
  __syncthreads();
  const float bb = sb[0];
  if (t < ZCH) {
    const float4 s = softmax4(twj, j0, j0 + t, bb);
    float* p = &P[t][0];
    float va = 1.f, vb = 1.f, vc = 1.f, vd = 1.f;
    p[0] = 1.f; p[8] = 1.f; p[16] = 1.f; p[24] = 1.f;
#pragma unroll
    for (int e = 1; e < 8; ++e) {
      va *= s.x; vb *= s.y; vc *= s.z; vd *= s.w;
      p[e] = va; p[8 + e] = vb; p[16 + e] = vc; p[24 + e] = vd;
    }
  }
  __syncthreads();
  if (t < NF) {
    const unsigned pk = pkS[t];
    const int p = pk & 255, q = (pk >> 8) & 255, r = (pk >> 16) & 255, s4 = pk >> 24;
    float z0 = 0.f, z1 = 0.f, z2 = 0.f, z3 = 0.f, z4 = 0.f;
#pragma unroll 2
    for (int jj = 0; jj < ZCH; ++jj) {
      const float* pp = &P[jj][0];
      const float pa0 = pp[p],       pa1 = pp[p + 1];
      const float pb0 = pp[8 + q],   pb1 = pp[8 + q + 1];
      const float pc0 = pp[16 + r],  pc1 = pp[16 + r + 1];
      const float pd0 = pp[24 + s4], pd1 = pp[24 + s4 + 1];
      const float cd = pc0 * pd0, ab = pa0 * pb0;
      z4 += pa0 * (pb0 * cd);
      z0 += pa1 * (pb0 * cd);
      z1 += pb1 * (pa0 * cd);
      z2 += pc1 * (ab * pd0);
      z3 += pd1 * (ab * pc0);
    }
    float* zb = Zg + (size_t)(b * NF + t) * 5;
    atomicAdd(zb + 0, z0); atomicAdd(zb + 1, z1); atomicAdd(zb + 2, z2);
    atomicAdd(zb + 3, z3); atomicAdd(zb + 4, z4);
  }
}

// ---------------- K2: 12-row tiles: wgt from phi(s_i).Z, h gathered from G, downsample
__global__ __launch_bounds__(256) void k_fuse(const int* __restrict__ x,
    const float* __restrict__ G, const float* __restrict__ biasp,
    const float* __restrict__ sw, const float* __restrict__ sb,
    const unsigned* __restrict__ featPk, const float* __restrict__ featCf,
    const float* __restrict__ Zg, float* __restrict__ out) {
  __shared__ __align__(16) float4 wgtS[12];
  __shared__ float tbS[12];
  __shared__ float Pr[12][32];
  __shared__ float Zl[NF * 5];
  __shared__ unsigned pkS[NF];
  __shared__ float cfS[NF];
  __shared__ int tokS[16];
  __shared__ float tpart[12][4];
  const int bx = blockIdx.x;
  const int b = bx / 342, j12 = bx % 342;
  const int t = threadIdx.x, d = t * 2, w = t >> 6, l = t & 63;
  const int r0 = 12 * j12;

  if (t < NF) { pkS[t] = featPk[t]; cfS[t] = featCf[t]; }
  for (int i2 = t; i2 < NF * 5; i2 += 256) Zl[i2] = Zg[(size_t)b * NF * 5 + i2];
  if (t < 15) {
    const int j = r0 + t;
    tokS[t] = (j < N_) ? x[b * N_ + j] : -1;
  }
  __syncthreads();

  // h rows via direct G gather (L2-resident); t-scores via hv.sw reduction (free)
  const float2 bp  = *(const float2*)(biasp + d);
  const float2 swv = *(const float2*)(sw + d);
  float2 hv[12];
#pragma unroll
  for (int q = 0; q < 12; ++q) {
    float2 a = make_float2(0.f, 0.f);
    if (r0 + q < N_) {
      a = bp;
#pragma unroll
      for (int k = 0; k < 4; ++k) {
        const int tk = tokS[q + k];
        if (tk >= 0) {
          const float2 g = *(const float2*)(G + ((size_t)k * 256 + tk) * 512 + d);
          a.x += g.x; a.y += g.y;
        }
      }
    }
    hv[q] = a;
  }
#pragma unroll
  for (int q = 0; q < 12; ++q) {
    float s = hv[q].x * swv.x + hv[q].y * swv.y;
#pragma unroll
    for (int off = 32; off > 0; off >>= 1) s += __shfl_xor(s, off);
    if (l == 0) tpart[q][w] = s;
  }
  __syncthreads();
  if (t < 12) tbS[t] = tpart[t][0] + tpart[t][1] + tpart[t][2] + tpart[t][3];
  __syncthreads();
  if (t < 12) {                          // powers of s_i for this tile's 12 rows
    const float4 s = softmax4(tbS, r0, r0 + t, sb[0]);
    float* p = &Pr[t][0];
    float va = 1.f, vb = 1.f, vc = 1.f, vd = 1.f;
    p[0] = 1.f; p[8] = 1.f; p[16] = 1.f; p[24] = 1.f;
#pragma unroll
    for (int e = 1; e < 8; ++e) {
      va *= s.x; vb *= s.y; vc *= s.z; vd *= s.w;
      p[e] = va; p[8 + e] = vb; p[16 + e] = vc; p[24 + e] = vd;
    }
  }
  __syncthreads();
  if (t < 192) {                         // 16 lanes per row evaluate phi . Z
    const int row = t >> 4, fi = t & 15;
    float n0 = 0.f, n1 = 0.f, n2 = 0.f, n3 = 0.f, dn = 0.f;
    const float* pr = &Pr[row][0];
    for (int f = fi; f < NF; f += 16) {
      const unsigned pk = pkS[f];
      const float val = cfS[f] * pr[pk & 255] * pr[8 + ((pk >> 8) & 255)]
                                * pr[16 + ((pk >> 16) & 255)] * pr[24 + (pk >> 24)];
      const float* z = &Zl[f * 5];
      n0 += val * z[0]; n1 += val * z[1]; n2 += val * z[2]; n3 += val * z[3];
      dn += val * z[4];
    }
#pragma unroll
    for (int m = 8; m >= 1; m >>= 1) {
      n0 += __shfl_xor(n0, m); n1 += __shfl_xor(n1, m); n2 += __shfl_xor(n2, m);
      n3 += __shfl_xor(n3, m); dn += __shfl_xor(dn, m);
    }
    if (fi == 0) {
      const float inv = 1.f / dn;
      wgtS[row] = make_float4(n0 * inv, n1 * inv, n2 * inv, n3 * inv);
    }
  }
  __syncthreads();

  float2 p2[6], p3[4], p4[3];
#pragma unroll
  for (int g = 0; g < 6; ++g) {
    p2[g].x = (hv[2 * g].x + hv[2 * g + 1].x) * 0.5f;
    p2[g].y = (hv[2 * g].y + hv[2 * g + 1].y) * 0.5f;
  }
#pragma unroll
  for (int g = 0; g < 4; ++g) {
    p3[g].x = (hv[3 * g].x + hv[3 * g + 1].x + hv[3 * g + 2].x) * (1.f / 3.f);
    p3[g].y = (hv[3 * g].y + hv[3 * g + 1].y + hv[3 * g + 2].y) * (1.f / 3.f);
  }
#pragma unroll
  for (int g = 0; g < 3; ++g) {
    p4[g].x = (hv[4 * g].x + hv[4 * g + 1].x + hv[4 * g + 2].x + hv[4 * g + 3].x) * 0.25f;
    p4[g].y = (hv[4 * g].y + hv[4 * g + 1].y + hv[4 * g + 2].y + hv[4 * g + 3].y) * 0.25f;
  }

#pragma unroll
  for (int o = 0; o < 3; ++o) {
    const int orow = j12 * 3 + o;
    if (orow < 1024) {
      float ox = 0.f, oy = 0.f;
#pragma unroll
      for (int rr = 0; rr < 4; ++rr) {
        const int r = 4 * o + rr;
        const float4 wv = wgtS[r];
        const float2 p1 = hv[r];
        const float2 q2 = p2[r >> 1];
        const float2 q3 = p3[r / 3];
        const float2 q4 = p4[o];
        ox += wv.x * p1.x + wv.y * q2.x + wv.z * q3.x + wv.w * q4.x;
        oy += wv.x * p1.y + wv.y * q2.y + wv.z * q3.y + wv.w * q4.y;
      }
      float2 ov; ov.x = ox * 0.25f; ov.y = oy * 0.25f;
      *(float2*)(out + (size_t)(b * 1024 + orow) * D_ + d) = ov;
    }
  }
}

extern "C" void kernel_launch(void* const* d_in, const int* in_sizes, int n_in,
                              void* d_out, int out_size, void* d_ws, size_t ws_size,
                              hipStream_t stream) {
  const int*   x       = (const int*)d_in[0];
  const float* emb     = (const float*)d_in[1];
  const float* conv_w  = (const float*)d_in[2];
  const float* conv_b  = (const float*)d_in[3];
  const float* proj_w  = (const float*)d_in[4];
  const float* proj_b  = (const float*)d_in[5];
  const float* score_w = (const float*)d_in[6];
  const float* score_b = (const float*)d_in[7];
  float* out = (float*)d_out;

  char* ws = (char*)d_ws;
  size_t off = 0;
  float*    G      = (float*)(ws + off); off += (size_t)4 * 256 * 512 * 4;  // 2 MB
  float*    bias   = (float*)(ws + off); off += (size_t)512 * 4;
  float*    Zg     = (float*)(ws + off); off += (size_t)B_ * NF * 5 * 4;    // 16.8 KB
  unsigned* featPk = (unsigned*)(ws + off); off += (size_t)1024;
  float*    featCf = (float*)(ws + off); off += (size_t)1024;
  (void)in_sizes; (void)n_in; (void)out_size; (void)ws_size;

  k_g<<<129, 256, 0, stream>>>(emb, proj_w, conv_w, conv_b, proj_b, G, bias, featPk, featCf, Zg);
  k_zphi<<<B_ * ZCHUNKS, 256, 0, stream>>>(x, G, bias, score_w, score_b, featPk, Zg);
  k_fuse<<<B_ * 342, 256, 0, stream>>>(x, G, bias, score_w, score_b, featPk, featCf, Zg, out);
}

// Round 3
// 137.126 us; speedup vs baseline: 1.2255x; 1.2255x over previous
//
#include <hip/hip_runtime.h>
#include <hip/hip_bf16.h>

#define B_ 4
#define N_ 4096
#define L_ 4104
#define D_ 512
#define BK 64
#define NF 210     // monomials of degree <=6 in 4 vars
#define ZCH 36     // k_zphi chunk length (multiple of 12 -> aligned pooling windows)
#define ZCHUNKS 114  // 114*36 == 4104 == L_
#define PST 37     // P LDS row stride (coprime with 32 -> conflict-free column reads)

typedef __attribute__((ext_vector_type(8))) short bf16x8;
typedef __attribute__((ext_vector_type(4))) float f32x4;

// ---------------- K0: G_k = bf16(emb*cw_k) @ bf16(W)^T  + bias' + feature table -------
__global__ __launch_bounds__(256) void k_g(const float* __restrict__ emb,
    const float* __restrict__ pw, const float* __restrict__ cwp,
    const float* __restrict__ cb, const float* __restrict__ pb,
    float* __restrict__ G, float* __restrict__ biasp,
    unsigned* __restrict__ featPk, float* __restrict__ featCf,
    float* __restrict__ Zg) {
  __shared__ __align__(16) __hip_bfloat16 As[2][64 * BK];
  __shared__ __align__(16) __hip_bfloat16 Bs[2][128 * BK];
  __shared__ __align__(16) float cwS[512];
  __shared__ float red[4];
  const int bx = blockIdx.x;
  const int t = threadIdx.x;
  const int w = t >> 6, l = t & 63;

  if (bx == 128) {                       // feature table + zero moment buffer
    for (int zi = t; zi < B_ * NF * 5; zi += 256) Zg[zi] = 0.f;
    if (t < NF) {
      int idx = 0, mp = 0, mq = 0, mr = 0, ms = 0;
      for (int m = 0; m <= 6; ++m)
        for (int p = m; p >= 0; --p)
          for (int q = m - p; q >= 0; --q)
            for (int r = m - p - q; r >= 0; --r) {
              const int s4 = m - p - q - r;
              if (idx == t) { mp = p; mq = q; mr = r; ms = s4; }
              ++idx;
            }
      featPk[t] = (unsigned)mp | ((unsigned)mq << 8) | ((unsigned)mr << 16) | ((unsigned)ms << 24);
      const float invf[7] = {1.f, 1.f, 0.5f, 1.f/6.f, 1.f/24.f, 1.f/120.f, 1.f/720.f};
      featCf[t] = invf[mp] * invf[mq] * invf[mr] * invf[ms];
    }
    return;
  }
  if (bx >= 64) {                        // bias'[o] = cb . W[o,:] + pb[o]
    const int o0 = (bx - 64) * 8;
    const float2 cv = *(const float2*)(cb + t * 2);
#pragma unroll
    for (int oo = 0; oo < 8; ++oo) {
      const int o = o0 + oo;
      const float2 wv = *(const float2*)(pw + (size_t)o * 512 + t * 2);
      float s = wv.x * cv.x + wv.y * cv.y;
#pragma unroll
      for (int off = 32; off > 0; off >>= 1) s += __shfl_xor(s, off);
      if (l == 0) red[w] = s;
      __syncthreads();
      if (t == 0) biasp[o] = red[0] + red[1] + red[2] + red[3] + pb[o];
      __syncthreads();
    }
    return;
  }

  const int m0 = (bx & 3) * 64;          // token tile
  const int n0 = ((bx >> 2) & 3) * 128;  // output-channel tile
  const int kp = bx >> 4;                // conv tap 0..3
  const int quad = l >> 4, r16 = l & 15;
  const int wc = w * 32;

  cwS[t]       = cwp[t * 4 + kp];
  cwS[t + 256] = cwp[(t + 256) * 4 + kp];

  f32x4 acc[4][2];
#pragma unroll
  for (int a = 0; a < 4; ++a)
#pragma unroll
    for (int bq = 0; bq < 2; ++bq) acc[a][bq] = (f32x4){0.f, 0.f, 0.f, 0.f};

  const int ra = t >> 2, ga0 = (t & 3) * 2;
  const int rb = t >> 1, gb0 = (t & 1) * 4;

#define STAGEG(buf, kb)                                                          \
  _Pragma("unroll")                                                              \
  for (int gi = 0; gi < 2; ++gi) {                                               \
    const int g = ga0 + gi;                                                      \
    const int c0 = (kb) + g * 8;                                                 \
    const float4 a0 = *(const float4*)(emb + (size_t)(m0 + ra) * 512 + c0);      \
    const float4 a1 = *(const float4*)(emb + (size_t)(m0 + ra) * 512 + c0 + 4);  \
    const float4 w0 = *(const float4*)(cwS + c0);                                \
    const float4 w1 = *(const float4*)(cwS + c0 + 4);                            \
    union { __hip_bfloat16 q[8]; bf16x8 v; } ua;                                 \
    ua.q[0] = __float2bfloat16(a0.x * w0.x); ua.q[1] = __float2bfloat16(a0.y * w0.y); \
    ua.q[2] = __float2bfloat16(a0.z * w0.z); ua.q[3] = __float2bfloat16(a0.w * w0.w); \
    ua.q[4] = __float2bfloat16(a1.x * w1.x); ua.q[5] = __float2bfloat16(a1.y * w1.y); \
    ua.q[6] = __float2bfloat16(a1.z * w1.z); ua.q[7] = __float2bfloat16(a1.w * w1.w); \
    *(bf16x8*)(&As[buf][ra * BK + ((g ^ (ra & 7)) * 8)]) = ua.v;                 \
  }                                                                              \
  _Pragma("unroll")                                                              \
  for (int gi = 0; gi < 4; ++gi) {                                               \
    const int g = gb0 + gi;                                                      \
    const int c0 = (kb) + g * 8;                                                 \
    const float4 b0 = *(const float4*)(pw + (size_t)(n0 + rb) * 512 + c0);       \
    const float4 b1 = *(const float4*)(pw + (size_t)(n0 + rb) * 512 + c0 + 4);   \
    union { __hip_bfloat16 q[8]; bf16x8 v; } ub;                                 \
    ub.q[0] = __float2bfloat16(b0.x); ub.q[1] = __float2bfloat16(b0.y);          \
    ub.q[2] = __float2bfloat16(b0.z); ub.q[3] = __float2bfloat16(b0.w);          \
    ub.q[4] = __float2bfloat16(b1.x); ub.q[5] = __float2bfloat16(b1.y);          \
    ub.q[6] = __float2bfloat16(b1.z); ub.q[7] = __float2bfloat16(b1.w);          \
    *(bf16x8*)(&Bs[buf][rb * BK + ((g ^ (rb & 7)) * 8)]) = ub.v;                 \
  }

  __syncthreads();        // cwS ready
  STAGEG(0, 0)
  __syncthreads();

#pragma unroll 1
  for (int kt = 0; kt < 8; ++kt) {
    const int cur = kt & 1;
    if (kt < 7) { STAGEG(1 - cur, (kt + 1) * BK) }
#pragma unroll
    for (int kk = 0; kk < 2; ++kk) {
      const int col_e = (kk * 32 + quad * 8) ^ ((r16 & 7) * 8);
      bf16x8 af[4], bfr[2];
#pragma unroll
      for (int ti = 0; ti < 4; ++ti)
        af[ti] = *(const bf16x8*)(&As[cur][(ti * 16 + r16) * BK + col_e]);
#pragma unroll
      for (int tj = 0; tj < 2; ++tj)
        bfr[tj] = *(const bf16x8*)(&Bs[cur][(wc + tj * 16 + r16) * BK + col_e]);
#pragma unroll
      for (int ti = 0; ti < 4; ++ti)
#pragma unroll
        for (int tj = 0; tj < 2; ++tj)
          acc[ti][tj] = __builtin_amdgcn_mfma_f32_16x16x32_bf16(af[ti], bfr[tj], acc[ti][tj], 0, 0, 0);
    }
    __syncthreads();
  }
#undef STAGEG

#pragma unroll
  for (int ti = 0; ti < 4; ++ti) {
    const int gi0 = m0 + ti * 16 + quad * 4;
#pragma unroll
    for (int tj = 0; tj < 2; ++tj) {
      const int go = n0 + wc + tj * 16 + r16;
#pragma unroll
      for (int r = 0; r < 4; ++r)
        G[((size_t)kp * 256 + gi0 + r) * 512 + go] = acc[ti][tj][r];
    }
  }
}

// ---------------- K1: TS[k][tok] = G_k[tok] . sw  (1024 wave-reduced dots), c0 --------
__global__ __launch_bounds__(256) void k_ts(const float* __restrict__ G,
    const float* __restrict__ biasp, const float* __restrict__ sw,
    float* __restrict__ TS, float* __restrict__ c0g) {
  __shared__ float red[4];
  const int bx = blockIdx.x;
  const int t = threadIdx.x, w = t >> 6, l = t & 63;
  if (bx == 128) {                       // c0 = biasp . sw
    const float2 a = *(const float2*)(biasp + t * 2);
    const float2 b = *(const float2*)(sw + t * 2);
    float s = a.x * b.x + a.y * b.y;
#pragma unroll
    for (int off = 32; off > 0; off >>= 1) s += __shfl_xor(s, off);
    if (l == 0) red[w] = s;
    __syncthreads();
    if (t == 0) c0g[0] = red[0] + red[1] + red[2] + red[3];
    return;
  }
  const float4 s0 = *(const float4*)(sw + l * 8);
  const float4 s1 = *(const float4*)(sw + l * 8 + 4);
#pragma unroll
  for (int rr = 0; rr < 2; ++rr) {
    const int row = bx * 8 + w * 2 + rr;
    const float4 g0 = *(const float4*)(G + (size_t)row * 512 + l * 8);
    const float4 g1 = *(const float4*)(G + (size_t)row * 512 + l * 8 + 4);
    float s = g0.x * s0.x + g0.y * s0.y + g0.z * s0.z + g0.w * s0.w
            + g1.x * s1.x + g1.y * s1.y + g1.z * s1.z + g1.w * s1.w;
#pragma unroll
    for (int off = 32; off > 0; off >>= 1) s += __shfl_xor(s, off);
    if (l == 0) TS[row] = s;
  }
}

// helper: 4-way softmax from a t-window in LDS
__device__ __forceinline__ float4 softmax4(const float* __restrict__ tw, int base,
                                           int i, float bb) {
  const float s0 = tw[i - base] + bb;
  const int j2 = i & ~1;
  const float s1 = (tw[j2 - base] + tw[j2 + 1 - base]) * 0.5f + bb;
  const int j3 = (i / 3) * 3;
  const float s2 = (tw[j3 - base] + tw[j3 + 1 - base] + tw[j3 + 2 - base]) * (1.f / 3.f) + bb;
  const int j4 = i & ~3;
  const float s3 = (tw[j4 - base] + tw[j4 + 1 - base] + tw[j4 + 2 - base] + tw[j4 + 3 - base]) * 0.25f + bb;
  const float m = fmaxf(fmaxf(s0, s1), fmaxf(s2, s3));
  const float e0 = __expf(s0 - m), e1 = __expf(s1 - m), e2 = __expf(s2 - m), e3 = __expf(s3 - m);
  const float inv = 1.f / (e0 + e1 + e2 + e3);
  return make_float4(e0 * inv, e1 * inv, e2 * inv, e3 * inv);
}

// ---------------- K2: j-side moments  Z[alpha] = sum_j s_j^alpha * [s_j;1]
// t-window from TS lookups; P transposed [32][PST] -> conflict-free column reads
__global__ __launch_bounds__(256) void k_zphi(const int* __restrict__ x,
    const float* __restrict__ TS, const float* __restrict__ c0g,
    const float* __restrict__ sb, const unsigned* __restrict__ featPk,
    float* __restrict__ Zg) {
  __shared__ float twj[ZCH];
  __shared__ float P[32][PST];
  __shared__ unsigned pkS[NF];
  __shared__ int tokS[ZCH + 3];
  const int bx = blockIdx.x;             // B_*ZCHUNKS
  const int b = bx / ZCHUNKS, jc = bx % ZCHUNKS;
  const int t = threadIdx.x;
  const int j0 = jc * ZCH;               // multiple of 12 -> pooling windows stay in-tile
  if (t < NF) pkS[t] = featPk[t];
  if (t < ZCH + 3) {
    const int j = j0 + t;
    tokS[t] = (j < N_) ? x[b * N_ + j] : -1;
  }
  __syncthreads();
  if (t < ZCH) {
    float tv = 0.f;
    if (j0 + t < N_) {
      tv = c0g[0];
#pragma unroll
      for (int k = 0; k < 4; ++k) {
        const int tk = tokS[t + k];
        if (tk >= 0) tv += TS[k * 256 + tk];
      }
    }
    twj[t] = tv;
  }
  __syncthreads();
  const float bb = sb[0];
  if (t < ZCH) {
    const float4 s = softmax4(twj, j0, j0 + t, bb);
    P[0][t] = 1.f; P[8][t] = 1.f; P[16][t] = 1.f; P[24][t] = 1.f;
    float va = 1.f, vb = 1.f, vc = 1.f, vd = 1.f;
#pragma unroll
    for (int e = 1; e < 8; ++e) {
      va *= s.x; vb *= s.y; vc *= s.z; vd *= s.w;
      P[e][t] = va; P[8 + e][t] = vb; P[16 + e][t] = vc; P[24 + e][t] = vd;
    }
  }
  __syncthreads();
  if (t < NF) {
    const unsigned pk = pkS[t];
    const int p = pk & 255, q = (pk >> 8) & 255, r = (pk >> 16) & 255, s4 = pk >> 24;
    const float* Ra0 = &P[p][0];       const float* Ra1 = &P[p + 1][0];
    const float* Rb0 = &P[8 + q][0];   const float* Rb1 = &P[8 + q + 1][0];
    const float* Rc0 = &P[16 + r][0];  const float* Rc1 = &P[16 + r + 1][0];
    const float* Rd0 = &P[24 + s4][0]; const float* Rd1 = &P[24 + s4 + 1][0];
    float z0 = 0.f, z1 = 0.f, z2 = 0.f, z3 = 0.f, z4 = 0.f;
#pragma unroll 4
    for (int jj = 0; jj < ZCH; ++jj) {
      const float pa0 = Ra0[jj], pa1 = Ra1[jj];
      const float pb0 = Rb0[jj], pb1 = Rb1[jj];
      const float pc0 = Rc0[jj], pc1 = Rc1[jj];
      const float pd0 = Rd0[jj], pd1 = Rd1[jj];
      const float cd = pc0 * pd0, ab = pa0 * pb0;
      z4 += pa0 * (pb0 * cd);
      z0 += pa1 * (pb0 * cd);
      z1 += pb1 * (pa0 * cd);
      z2 += pc1 * (ab * pd0);
      z3 += pd1 * (ab * pc0);
    }
    float* zb = Zg + (size_t)(b * NF + t) * 5;
    atomicAdd(zb + 0, z0); atomicAdd(zb + 1, z1); atomicAdd(zb + 2, z2);
    atomicAdd(zb + 3, z3); atomicAdd(zb + 4, z4);
  }
}

// ---------------- K3: 12-row tiles: wgt from phi(s_i).Z, h gathered from G, downsample
__global__ __launch_bounds__(256) void k_fuse(const int* __restrict__ x,
    const float* __restrict__ G, const float* __restrict__ biasp,
    const float* __restrict__ TS, const float* __restrict__ c0g,
    const float* __restrict__ sb, const unsigned* __restrict__ featPk,
    const float* __restrict__ featCf, const float* __restrict__ Zg,
    float* __restrict__ out) {
  __shared__ __align__(16) float4 wgtS[12];
  __shared__ float tbS[12];
  __shared__ float Pr[12][33];
  __shared__ float Zl[NF * 5];
  __shared__ unsigned pkS[NF];
  __shared__ float cfS[NF];
  __shared__ int tokS[16];
  const int bx = blockIdx.x;
  const int b = bx / 342, j12 = bx % 342;
  const int t = threadIdx.x, d = t * 2;
  const int r0 = 12 * j12;

  if (t < NF) { pkS[t] = featPk[t]; cfS[t] = featCf[t]; }
  for (int i2 = t; i2 < NF * 5; i2 += 256) Zl[i2] = Zg[(size_t)b * NF * 5 + i2];
  if (t < 15) {
    const int j = r0 + t;
    tokS[t] = (j < N_) ? x[b * N_ + j] : -1;
  }
  __syncthreads();

  // h rows via direct G gather (L2-resident); t-scores via TS lookup
  const float2 bp = *(const float2*)(biasp + d);
  float2 hv[12];
#pragma unroll
  for (int q = 0; q < 12; ++q) {
    float2 a = make_float2(0.f, 0.f);
    if (r0 + q < N_) {
      a = bp;
#pragma unroll
      for (int k = 0; k < 4; ++k) {
        const int tk = tokS[q + k];
        if (tk >= 0) {
          const float2 g = *(const float2*)(G + ((size_t)k * 256 + tk) * 512 + d);
          a.x += g.x; a.y += g.y;
        }
      }
    }
    hv[q] = a;
  }

  if (t < 12) {
    float tv = 0.f;
    if (r0 + t < N_) {
      tv = c0g[0];
#pragma unroll
      for (int k = 0; k < 4; ++k) {
        const int tk = tokS[t + k];
        if (tk >= 0) tv += TS[k * 256 + tk];
      }
    }
    tbS[t] = tv;
  }
  __syncthreads();
  if (t < 12) {                          // powers of s_i for this tile's 12 rows
    const float4 s = softmax4(tbS, r0, r0 + t, sb[0]);
    float* p = &Pr[t][0];
    float va = 1.f, vb = 1.f, vc = 1.f, vd = 1.f;
    p[0] = 1.f; p[8] = 1.f; p[16] = 1.f; p[24] = 1.f;
#pragma unroll
    for (int e = 1; e < 8; ++e) {
      va *= s.x; vb *= s.y; vc *= s.z; vd *= s.w;
      p[e] = va; p[8 + e] = vb; p[16 + e] = vc; p[24 + e] = vd;
    }
  }
  __syncthreads();
  if (t < 192) {                         // 16 lanes per row evaluate phi . Z
    const int row = t >> 4, fi = t & 15;
    float n0 = 0.f, n1 = 0.f, n2 = 0.f, n3 = 0.f, dn = 0.f;
    const float* pr = &Pr[row][0];
    for (int f = fi; f < NF; f += 16) {
      const unsigned pk = pkS[f];
      const float val = cfS[f] * pr[pk & 255] * pr[8 + ((pk >> 8) & 255)]
                                * pr[16 + ((pk >> 16) & 255)] * pr[24 + (pk >> 24)];
      const float* z = &Zl[f * 5];
      n0 += val * z[0]; n1 += val * z[1]; n2 += val * z[2]; n3 += val * z[3];
      dn += val * z[4];
    }
#pragma unroll
    for (int m = 8; m >= 1; m >>= 1) {
      n0 += __shfl_xor(n0, m); n1 += __shfl_xor(n1, m); n2 += __shfl_xor(n2, m);
      n3 += __shfl_xor(n3, m); dn += __shfl_xor(dn, m);
    }
    if (fi == 0) {
      const float inv = 1.f / dn;
      wgtS[row] = make_float4(n0 * inv, n1 * inv, n2 * inv, n3 * inv);
    }
  }
  __syncthreads();

  float2 p2[6], p3[4], p4[3];
#pragma unroll
  for (int g = 0; g < 6; ++g) {
    p2[g].x = (hv[2 * g].x + hv[2 * g + 1].x) * 0.5f;
    p2[g].y = (hv[2 * g].y + hv[2 * g + 1].y) * 0.5f;
  }
#pragma unroll
  for (int g = 0; g < 4; ++g) {
    p3[g].x = (hv[3 * g].x + hv[3 * g + 1].x + hv[3 * g + 2].x) * (1.f / 3.f);
    p3[g].y = (hv[3 * g].y + hv[3 * g + 1].y + hv[3 * g + 2].y) * (1.f / 3.f);
  }
#pragma unroll
  for (int g = 0; g < 3; ++g) {
    p4[g].x = (hv[4 * g].x + hv[4 * g + 1].x + hv[4 * g + 2].x + hv[4 * g + 3].x) * 0.25f;
    p4[g].y = (hv[4 * g].y + hv[4 * g + 1].y + hv[4 * g + 2].y + hv[4 * g + 3].y) * 0.25f;
  }

#pragma unroll
  for (int o = 0; o < 3; ++o) {
    const int orow = j12 * 3 + o;
    if (orow < 1024) {
      float ox = 0.f, oy = 0.f;
#pragma unroll
      for (int rr = 0; rr < 4; ++rr) {
        const int r = 4 * o + rr;
        const float4 wv = wgtS[r];
        const float2 p1 = hv[r];
        const float2 q2 = p2[r >> 1];
        const float2 q3 = p3[r / 3];
        const float2 q4 = p4[o];
        ox += wv.x * p1.x + wv.y * q2.x + wv.z * q3.x + wv.w * q4.x;
        oy += wv.x * p1.y + wv.y * q2.y + wv.z * q3.y + wv.w * q4.y;
      }
      float2 ov; ov.x = ox * 0.25f; ov.y = oy * 0.25f;
      *(float2*)(out + (size_t)(b * 1024 + orow) * D_ + d) = ov;
    }
  }
}

extern "C" void kernel_launch(void* const* d_in, const int* in_sizes, int n_in,
                              void* d_out, int out_size, void* d_ws, size_t ws_size,
                              hipStream_t stream) {
  const int*   x       = (const int*)d_in[0];
  const float* emb     = (const float*)d_in[1];
  const float* conv_w  = (const float*)d_in[2];
  const float* conv_b  = (const float*)d_in[3];
  const float* proj_w  = (const float*)d_in[4];
  const float* proj_b  = (const float*)d_in[5];
  const float* score_w = (const float*)d_in[6];
  const float* score_b = (const float*)d_in[7];
  float* out = (float*)d_out;

  char* ws = (char*)d_ws;
  size_t off = 0;
  float*    G      = (float*)(ws + off); off += (size_t)4 * 256 * 512 * 4;  // 2 MB
  float*    bias   = (float*)(ws + off); off += (size_t)512 * 4;
  float*    Zg     = (float*)(ws + off); off += (size_t)B_ * NF * 5 * 4;    // 16.8 KB
  unsigned* featPk = (unsigned*)(ws + off); off += (size_t)1024;
  float*    featCf = (float*)(ws + off); off += (size_t)1024;
  float*    TS     = (float*)(ws + off); off += (size_t)1024 * 4;           // 4 KB
  float*    c0     = (float*)(ws + off); off += (size_t)16;
  (void)in_sizes; (void)n_in; (void)out_size; (void)ws_size;

  k_g<<<129, 256, 0, stream>>>(emb, proj_w, conv_w, conv_b, proj_b, G, bias, featPk, featCf, Zg);
  k_ts<<<129, 256, 0, stream>>>(G, bias, score_w, TS, c0);
  k_zphi<<<B_ * ZCHUNKS, 256, 0, stream>>>(x, TS, c0, score_b, featPk, Zg);
  k_fuse<<<B_ * 342, 256, 0, stream>>>(x, G, bias, TS, c0, score_b, featPk, featCf, Zg, out);
}